// Round 12
// baseline (170.669 us; speedup 1.0000x reference)
//
#include <hip/hip_runtime.h>

// LSTM: HIDDEN=128, SEQ=7, BATCH=65536. fp32 in/out.
//
// R19 (= R18 resubmit, round 11 died in the broker unrun; conservative
// syntax: no alignbit builtin, union packing instead of bit_cast).
// R18 theory: LDS-pipe-bound. R15(8w)=100us vs R17(16w)=94us => limiter
// is the per-CU shared LDS unit (~240 LDS-cyc/wave/t), not latency.
//  * x via per-lane GLOBAL loads (VMEM pipe, L1-resident): xs LDS buffer
//    and its 2 b128 reads/t deleted.
//  * h-staging writes paired: DPP quad_perm (VALU) exchanges lane-pair
//    halves -> 1 ds_write_b32 per (mt,p) instead of 2 strided b16;
//    ~4-way write conflicts -> ~1-2 way.
//  * Tw/Tb[8][16] split (16B entries): 4-way -> 2-way conflicts.
// Unchanged: (512,4) 16 waves/CU (VGPR 64+64 AGPR = cap, no spill), BT=32,
// weight-stationary bw in AGPRs, MFMA-pred side column (Wo LDS), packed
// exp2 fused-reciprocal epilogue, fp16 h dbuf LDS, 1 barrier/t.

#define SEQ 7
#define BT 32

typedef _Float16 half8 __attribute__((ext_vector_type(8)));
typedef float floatx4 __attribute__((ext_vector_type(4)));
typedef float floatx2 __attribute__((ext_vector_type(2)));

__device__ __forceinline__ floatx4 mfma16(half8 a, half8 b, floatx4 c) {
  return __builtin_amdgcn_mfma_f32_16x16x32_f16(a, b, c, 0, 0, 0);
}

#define LOG2E 1.4426950408889634f
#define K2 2.885390081777927f  // 2*log2e

__device__ __forceinline__ floatx2 pexp2m(floatx2 v) {
  floatx2 r;
  r.x = __builtin_amdgcn_exp2f(-v.x);
  r.y = __builtin_amdgcn_exp2f(-v.y);
  return r;
}
__device__ __forceinline__ floatx2 prcp(floatx2 v) {
  floatx2 r;
  r.x = __builtin_amdgcn_rcpf(v.x);
  r.y = __builtin_amdgcn_rcpf(v.y);
  return r;
}

// Pack W_hh [512][128] fp32 -> B-fragment-major fp16, prescaled (idx<65536):
//   Bp[((nt*4+kk)*64 + lane)*8 + jj] = S(g) * Whh[j][k]
//   nt=g*8+w, j=g*128+w*16+col, k=32kk+8quad+jj.
// idx in [65536, 69632): W_out hi/lo fragments, col-0-only 16-col tile.
__global__ void pack_kernel(const float* __restrict__ Whh,
                            const float* __restrict__ Wout,
                            _Float16* __restrict__ Bp) {
  int idx = blockIdx.x * 256 + threadIdx.x;  // 0..69631
  if (idx < 65536) {
    int jj = idx & 7;
    int lane = (idx >> 3) & 63;
    int kk = (idx >> 9) & 3;
    int nt = idx >> 11;  // 0..31
    int g = nt >> 3, w = nt & 7;
    int col = lane & 15, quad = lane >> 4;
    int j = g * 128 + w * 16 + col;
    int k = 32 * kk + 8 * quad + jj;
    float S = (g == 2) ? K2 : LOG2E;
    Bp[idx] = (_Float16)(S * Whh[j * 128 + k]);
  } else {
    int pos = idx - 65536;  // 0..4095
    int hl = pos >> 11;     // 0 = hi, 1 = lo
    int e = pos & 2047;
    int jj = e & 7;
    int lane = (e >> 3) & 63;
    int kk = e >> 9;
    int col = lane & 15, quad = lane >> 4;
    int k = 32 * kk + 8 * quad + jj;
    float wv = Wout[k];
    _Float16 hi = (_Float16)wv;
    _Float16 v = hl ? (_Float16)(wv - (float)hi) : hi;
    Bp[idx] = (col == 0) ? v : (_Float16)0.0f;
  }
}

__launch_bounds__(512, 4)
__global__ void lstm_kernel(const float* __restrict__ x,
                            const float* __restrict__ x0,
                            const float* __restrict__ Wih,
                            const float* __restrict__ bih,
                            const float* __restrict__ bhh,
                            const float* __restrict__ boutp,
                            const _Float16* __restrict__ Bp,
                            float* __restrict__ out) {
  // h staged fp16, double-buffered, 272B row stride (+8 pad).
  __shared__ _Float16 Ah[2][BT][136];  // 17,408 B
  __shared__ _Float16 Wo[4096];        // 8 KB W_out hi/lo B-fragments
  __shared__ floatx4 Tw[8][16];        // 2 KB prescaled wih per (w,col)
  __shared__ floatx4 Tb[8][16];        // 2 KB prescaled bias per (w,col)

  const int tid = threadIdx.x;
  const int w = tid >> 6;  // wave 0..7: owns hcols [16w, 16w+16)
  const int lane = tid & 63;
  const int col = lane & 15;
  const int quad = lane >> 4;
  const int rowbase = blockIdx.x * BT;
  const bool odd = (lane & 1) != 0;

  // stage W_out fragments into LDS (512 x 16B)
  ((half8*)Wo)[tid] = ((const half8*)(Bp + 65536))[tid];

  // build per-(w,col) prescaled wih/bias tables (16B entries -> 2-way)
  if (tid < 128) {
    int tw = tid >> 4, tc = tid & 15;
    float* pw = (float*)&Tw[tw][tc];
    float* pb = (float*)&Tb[tw][tc];
#pragma unroll
    for (int g = 0; g < 4; ++g) {
      int j = g * 128 + tw * 16 + tc;
      float S = (g == 2) ? K2 : LOG2E;
      pw[g] = S * Wih[j];
      pb[g] = S * (bih[j] + bhh[j]);
    }
  }

  // Gate-GEMM weight fragments: 64 regs (AGPR), loaded once.
  half8 bw[4][4];
#pragma unroll
  for (int g = 0; g < 4; ++g)
#pragma unroll
    for (int kk = 0; kk < 4; ++kk)
      bw[g][kk] =
          *(const half8*)(Bp + (((g * 8 + w) * 4 + kk) * 64 + lane) * 8);

  const float bout = boutp[0];

  // Scaled cell state c~ = 2log2e*c, pair-major float2 -> 8 registers.
  floatx2 c2[2][2];
#pragma unroll
  for (int mt = 0; mt < 2; ++mt)
#pragma unroll
    for (int p = 0; p < 2; ++p) c2[mt][p] = (floatx2){0.f, 0.f};

  __syncthreads();  // Wo/Tw/Tb ready (Ah zero-init unneeded: t=0 skips GEMM)

#pragma unroll 1
  for (int t = 0; t < SEQ; ++t) {
    const int cur = t & 1, nxt = cur ^ 1;

#pragma unroll
    for (int mt = 0; mt < 2; ++mt) {
      // x for the 4 rows this lane covers: per-lane GLOBAL loads
      // (L1-resident after first touch; VMEM pipe, not LDS).
      const int rowoff = rowbase + mt * 16 + quad * 4;
      float xr0, xr1, xr2, xr3;
      if (t == 0) {
        xr0 = x0[rowoff + 0];
        xr1 = x0[rowoff + 1];
        xr2 = x0[rowoff + 2];
        xr3 = x0[rowoff + 3];
      } else {
        xr0 = x[(size_t)(rowoff + 0) * 7 + (t - 1)];
        xr1 = x[(size_t)(rowoff + 1) * 7 + (t - 1)];
        xr2 = x[(size_t)(rowoff + 2) * 7 + (t - 1)];
        xr3 = x[(size_t)(rowoff + 3) * 7 + (t - 1)];
      }
      floatx4 xq = {xr0, xr1, xr2, xr3};

      // wih/bias from LDS (volatile -> stays transient; 2-way max).
      floatx4 wihv = *(volatile const floatx4*)&Tw[w][col];
      floatx4 biasv = *(volatile const floatx4*)&Tb[w][col];

      // acc init = x*W_ih + bias (prescaled, packed fma) -> MFMA C.
      floatx4 acc[4];
#pragma unroll
      for (int g = 0; g < 4; ++g) acc[g] = xq * wihv[g] + biasv[g];

      const bool dopred = (w < 2) && (mt == w);  // wave-uniform

      if (t != 0) {  // h(0)=0: skip GEMM at t=0
        floatx4 ap = (floatx4){0.f, 0.f, 0.f, 0.f};  // pred(t-1) partial
#pragma unroll
        for (int kk = 0; kk < 4; ++kk) {
          half8 ah =
              *(const half8*)&Ah[cur][mt * 16 + col][kk * 32 + quad * 8];
#pragma unroll
          for (int g = 0; g < 4; ++g) acc[g] = mfma16(ah, bw[g][kk], acc[g]);
          if (dopred) {
            half8 bo0 = *(const half8*)&Wo[(kk * 64 + lane) * 8];
            half8 bo1 = *(const half8*)&Wo[2048 + (kk * 64 + lane) * 8];
            ap = mfma16(ah, bo0, ap);
            ap = mfma16(ah, bo1, ap);
          }
        }
        if (dopred && col == 0) {
#pragma unroll
          for (int r = 0; r < 4; ++r)
            out[(size_t)(rowbase + mt * 16 + quad * 4 + r) * 7 + (t - 1)] =
                ap[r] + bout;
        }
      }

      // Fused-reciprocal cell update, PACKED pairs (r01, r23).
      const floatx2 one2 = {1.0f, 1.0f};
      const floatx2 k22 = {K2, K2};
#pragma unroll
      for (int p = 0; p < 2; ++p) {
        floatx2 Gi, Gf, Gg, Go;
        Gi.x = acc[0][2 * p];
        Gi.y = acc[0][2 * p + 1];
        Gf.x = acc[1][2 * p];
        Gf.y = acc[1][2 * p + 1];
        Gg.x = acc[2][2 * p];
        Gg.y = acc[2][2 * p + 1];
        Go.x = acc[3][2 * p];
        Go.y = acc[3][2 * p + 1];
        floatx2 A = pexp2m(Gi);
        floatx2 Bv = pexp2m(Gf);
        floatx2 Cv = pexp2m(Gg);
        floatx2 Dv = pexp2m(Go);
        floatx2 a1 = A + one2;
        floatx2 b1 = Bv + one2;
        floatx2 c1 = Cv + one2;
        floatx2 ac = a1 * c1;
        floatx2 t1 = k22 - Cv * k22;
        floatx2 num = c2[mt][p] * ac + t1 * b1;
        floatx2 den = ac * b1;
        floatx2 cn = num * prcp(den);
        c2[mt][p] = cn;
        floatx2 E = pexp2m(cn);
        floatx2 de = (Dv + one2) * (E + one2);
        floatx2 hn = (one2 - E) * prcp(de);

        // Paired h-staging write: lane-pair (col, col^1) exchanges packed
        // pairs via DPP quad_perm [1,0,3,2] (VALU pipe), each lane then
        // writes ONE b32: even lane -> row 2p cols {c,c+1}, odd lane ->
        // row 2p+1 cols {c,c+1}.
        union {
          _Float16 h[2];
          unsigned int u;
        } pk;
        pk.h[0] = (_Float16)hn.x;  // row 2p,   own col
        pk.h[1] = (_Float16)hn.y;  // row 2p+1, own col
        unsigned int t0 = pk.u;
        unsigned int t1x = (unsigned int)__builtin_amdgcn_mov_dpp(
            (int)t0, 0xB1, 0xF, 0xF, true);  // partner's packed pair
        unsigned int rot = (t1x >> 16) | (t1x << 16);
        unsigned int sa = odd ? rot : t0;
        unsigned int sb = odd ? t0 : rot;
        unsigned int res = (sa & 0xFFFFu) | (sb & 0xFFFF0000u);
        const int row = mt * 16 + quad * 4 + 2 * p + (odd ? 1 : 0);
        *(unsigned int*)&Ah[nxt][row][w * 16 + (col & ~1)] = res;
      }
    }
    // single barrier per t: h staging complete
    __syncthreads();
  }

  // tail: pred(6) from h(6) staged in Ah[SEQ&1] (= Ah[1])
  if (w < 2) {
    const int mt = w;
    floatx4 ap = (floatx4){0.f, 0.f, 0.f, 0.f};
#pragma unroll
    for (int kk = 0; kk < 4; ++kk) {
      half8 ah = *(const half8*)&Ah[1][mt * 16 + col][kk * 32 + quad * 8];
      half8 bo0 = *(const half8*)&Wo[(kk * 64 + lane) * 8];
      half8 bo1 = *(const half8*)&Wo[2048 + (kk * 64 + lane) * 8];
      ap = mfma16(ah, bo0, ap);
      ap = mfma16(ah, bo1, ap);
    }
    if (col == 0) {
#pragma unroll
      for (int r = 0; r < 4; ++r)
        out[(size_t)(rowbase + mt * 16 + quad * 4 + r) * 7 + 6] =
            ap[r] + bout;
    }
  }
}

extern "C" void kernel_launch(void* const* d_in, const int* in_sizes, int n_in,
                              void* d_out, int out_size, void* d_ws,
                              size_t ws_size, hipStream_t stream) {
  const float* x = (const float*)d_in[0];
  const float* x0 = (const float*)d_in[1];
  const float* Wih = (const float*)d_in[2];
  const float* Whh = (const float*)d_in[3];
  const float* bih = (const float*)d_in[4];
  const float* bhh = (const float*)d_in[5];
  const float* Wout = (const float*)d_in[6];
  const float* bout = (const float*)d_in[7];
  float* out = (float*)d_out;
  _Float16* Bp = (_Float16*)d_ws;  // 136 KB packed weights + wout frags

  pack_kernel<<<272, 256, 0, stream>>>(Whh, Wout, Bp);
  lstm_kernel<<<65536 / BT, 512, 0, stream>>>(x, x0, Wih, bih, bhh, bout, Bp,
                                              out);
}

// Round 13
// 148.375 us; speedup vs baseline: 1.1503x; 1.1503x over previous
//
#include <hip/hip_runtime.h>

// LSTM: HIDDEN=128, SEQ=7, BATCH=65536. fp32 in/out.
//
// R20: R17 (94.4us, proven spill-free) + pressure-FREE LDS-conflict cuts.
// R19 post-mortem: DPP pairing + in-loop global x loads cost transient
// regs at the zero-slack 128 cap -> 26MB scratch WRITE, 120us regression.
// Rule: at 64 arch + 64 AGPR, any feature costing >2 transient regs spills.
//  * Tw/Tb split into [8][16] 16B-entry tables (4-way -> 2-way reads).
//  * h-staging same-dword conflict fix, zero live-range cost: odd lanes
//    swap the ROW ORDER of their two b16 stores, so adjacent lanes hit
//    different rows (banks 4 apart) in each store instruction.
//  * Everything else identical to R17: xs via LDS dbuf, per-mt volatile
//    table reads, (512,4) 16 waves/CU, BT=32, weight-stationary bw in
//    AGPRs, MFMA-pred side column (Wo LDS), packed exp2 fused-reciprocal
//    epilogue, 1 barrier/t.

#define SEQ 7
#define BT 32

typedef _Float16 half8 __attribute__((ext_vector_type(8)));
typedef float floatx4 __attribute__((ext_vector_type(4)));
typedef float floatx2 __attribute__((ext_vector_type(2)));

__device__ __forceinline__ floatx4 mfma16(half8 a, half8 b, floatx4 c) {
  return __builtin_amdgcn_mfma_f32_16x16x32_f16(a, b, c, 0, 0, 0);
}

#define LOG2E 1.4426950408889634f
#define K2 2.885390081777927f  // 2*log2e

__device__ __forceinline__ floatx2 pexp2m(floatx2 v) {
  floatx2 r;
  r.x = __builtin_amdgcn_exp2f(-v.x);
  r.y = __builtin_amdgcn_exp2f(-v.y);
  return r;
}
__device__ __forceinline__ floatx2 prcp(floatx2 v) {
  floatx2 r;
  r.x = __builtin_amdgcn_rcpf(v.x);
  r.y = __builtin_amdgcn_rcpf(v.y);
  return r;
}

// Pack W_hh [512][128] fp32 -> B-fragment-major fp16, prescaled (idx<65536):
//   Bp[((nt*4+kk)*64 + lane)*8 + jj] = S(g) * Whh[j][k]
//   nt=g*8+w, j=g*128+w*16+col, k=32kk+8quad+jj.
// idx in [65536, 69632): W_out hi/lo fragments, col-0-only 16-col tile.
__global__ void pack_kernel(const float* __restrict__ Whh,
                            const float* __restrict__ Wout,
                            _Float16* __restrict__ Bp) {
  int idx = blockIdx.x * 256 + threadIdx.x;  // 0..69631
  if (idx < 65536) {
    int jj = idx & 7;
    int lane = (idx >> 3) & 63;
    int kk = (idx >> 9) & 3;
    int nt = idx >> 11;  // 0..31
    int g = nt >> 3, w = nt & 7;
    int col = lane & 15, quad = lane >> 4;
    int j = g * 128 + w * 16 + col;
    int k = 32 * kk + 8 * quad + jj;
    float S = (g == 2) ? K2 : LOG2E;
    Bp[idx] = (_Float16)(S * Whh[j * 128 + k]);
  } else {
    int pos = idx - 65536;  // 0..4095
    int hl = pos >> 11;     // 0 = hi, 1 = lo
    int e = pos & 2047;
    int jj = e & 7;
    int lane = (e >> 3) & 63;
    int kk = e >> 9;
    int col = lane & 15, quad = lane >> 4;
    int k = 32 * kk + 8 * quad + jj;
    float wv = Wout[k];
    _Float16 hi = (_Float16)wv;
    _Float16 v = hl ? (_Float16)(wv - (float)hi) : hi;
    Bp[idx] = (col == 0) ? v : (_Float16)0.0f;
  }
}

__launch_bounds__(512, 4)
__global__ void lstm_kernel(const float* __restrict__ x,
                            const float* __restrict__ x0,
                            const float* __restrict__ Wih,
                            const float* __restrict__ bih,
                            const float* __restrict__ bhh,
                            const float* __restrict__ boutp,
                            const _Float16* __restrict__ Bp,
                            float* __restrict__ out) {
  // h staged fp16, double-buffered, 272B row stride (+8 pad).
  __shared__ _Float16 Ah[2][BT][136];  // 17,408 B
  __shared__ float xs[2][BT];          // 256 B
  __shared__ _Float16 Wo[4096];        // 8 KB W_out hi/lo B-fragments
  __shared__ floatx4 Tw[8][16];        // 2 KB prescaled wih per (w,col)
  __shared__ floatx4 Tb[8][16];        // 2 KB prescaled bias per (w,col)

  const int tid = threadIdx.x;
  const int w = tid >> 6;  // wave 0..7: owns hcols [16w, 16w+16)
  const int lane = tid & 63;
  const int col = lane & 15;
  const int quad = lane >> 4;
  const int rowbase = blockIdx.x * BT;
  const int odd = lane & 1;

  // stage W_out fragments into LDS (512 x 16B)
  ((half8*)Wo)[tid] = ((const half8*)(Bp + 65536))[tid];

  // build per-(w,col) prescaled wih/bias tables (16B entries -> 2-way)
  if (tid < 128) {
    int tw = tid >> 4, tc = tid & 15;
    float* pw = (float*)&Tw[tw][tc];
    float* pb = (float*)&Tb[tw][tc];
#pragma unroll
    for (int g = 0; g < 4; ++g) {
      int j = g * 128 + tw * 16 + tc;
      float S = (g == 2) ? K2 : LOG2E;
      pw[g] = S * Wih[j];
      pb[g] = S * (bih[j] + bhh[j]);
    }
  }

  // Gate-GEMM weight fragments: 64 regs (AGPR), loaded once.
  half8 bw[4][4];
#pragma unroll
  for (int g = 0; g < 4; ++g)
#pragma unroll
    for (int kk = 0; kk < 4; ++kk)
      bw[g][kk] =
          *(const half8*)(Bp + (((g * 8 + w) * 4 + kk) * 64 + lane) * 8);

  const float bout = boutp[0];

  // Scaled cell state c~ = 2log2e*c, pair-major float2 -> 8 registers.
  floatx2 c2[2][2];
#pragma unroll
  for (int mt = 0; mt < 2; ++mt)
#pragma unroll
    for (int p = 0; p < 2; ++p) c2[mt][p] = (floatx2){0.f, 0.f};

  if (tid < BT) xs[0][tid] = x0[rowbase + tid];  // t=0 consumes x0
  __syncthreads();

#pragma unroll 1
  for (int t = 0; t < SEQ; ++t) {
    const int cur = t & 1, nxt = cur ^ 1;

    // prefetch input for t+1 (consumes x[:, t])
    if (t + 1 < SEQ && tid < BT) {
      xs[nxt][tid] = x[(size_t)(rowbase + tid) * 7 + t];
    }

#pragma unroll
    for (int mt = 0; mt < 2; ++mt) {
      // x for the 4 rows (mt*16 + quad*4 + r) this lane covers.
      floatx4 xq = *(const floatx4*)&xs[cur][mt * 16 + quad * 4];

      // wih/bias from LDS, volatile so they stay transient (no re-hoist);
      // 16B entries -> at most 2-way, col-aliases broadcast.
      floatx4 wihv = *(volatile const floatx4*)&Tw[w][col];
      floatx4 biasv = *(volatile const floatx4*)&Tb[w][col];

      // acc init = x*W_ih + bias (prescaled) -> MFMA C operand.
      floatx4 acc[4];
#pragma unroll
      for (int g = 0; g < 4; ++g)
#pragma unroll
        for (int r = 0; r < 4; ++r)
          acc[g][r] = __builtin_fmaf(wihv[g], xq[r], biasv[g]);

      const bool dopred = (w < 2) && (mt == w);  // wave-uniform

      if (t != 0) {  // h(0)=0: skip GEMM at t=0
        floatx4 ap = (floatx4){0.f, 0.f, 0.f, 0.f};  // pred(t-1) partial
#pragma unroll
        for (int kk = 0; kk < 4; ++kk) {
          half8 ah =
              *(const half8*)&Ah[cur][mt * 16 + col][kk * 32 + quad * 8];
#pragma unroll
          for (int g = 0; g < 4; ++g) acc[g] = mfma16(ah, bw[g][kk], acc[g]);
          if (dopred) {
            half8 bo0 = *(const half8*)&Wo[(kk * 64 + lane) * 8];
            half8 bo1 = *(const half8*)&Wo[2048 + (kk * 64 + lane) * 8];
            ap = mfma16(ah, bo0, ap);
            ap = mfma16(ah, bo1, ap);
          }
        }
        if (dopred && col == 0) {
#pragma unroll
          for (int r = 0; r < 4; ++r)
            out[(size_t)(rowbase + mt * 16 + quad * 4 + r) * 7 + (t - 1)] =
                ap[r] + bout;
        }
      }

      // Fused-reciprocal cell update, PACKED pairs (r01, r23).
      const floatx2 one2 = {1.0f, 1.0f};
      const floatx2 k22 = {K2, K2};
#pragma unroll
      for (int p = 0; p < 2; ++p) {
        floatx2 Gi, Gf, Gg, Go;
        Gi.x = acc[0][2 * p];
        Gi.y = acc[0][2 * p + 1];
        Gf.x = acc[1][2 * p];
        Gf.y = acc[1][2 * p + 1];
        Gg.x = acc[2][2 * p];
        Gg.y = acc[2][2 * p + 1];
        Go.x = acc[3][2 * p];
        Go.y = acc[3][2 * p + 1];
        floatx2 A = pexp2m(Gi);
        floatx2 Bv = pexp2m(Gf);
        floatx2 Cv = pexp2m(Gg);
        floatx2 Dv = pexp2m(Go);
        floatx2 a1 = A + one2;
        floatx2 b1 = Bv + one2;
        floatx2 c1 = Cv + one2;
        floatx2 ac = a1 * c1;
        floatx2 t1 = k22 - Cv * k22;
        floatx2 num = c2[mt][p] * ac + t1 * b1;
        floatx2 den = ac * b1;
        floatx2 cn = num * prcp(den);
        c2[mt][p] = cn;
        floatx2 E = pexp2m(cn);
        floatx2 de = (Dv + one2) * (E + one2);
        floatx2 hn = (one2 - E) * prcp(de);

        // stage h_new (fp16), rows 2p & 2p+1 at col 16w+col.
        // Conflict fix (zero reg cost): odd lanes store rows in swapped
        // order so adjacent lanes (col, col+1) never write the same dword
        // in the same store instruction.
        const int rbase = mt * 16 + quad * 4 + 2 * p;
        _Float16 hx = (_Float16)hn.x;  // row 2p value
        _Float16 hy = (_Float16)hn.y;  // row 2p+1 value
        Ah[nxt][rbase + odd][w * 16 + col] = odd ? hy : hx;
        Ah[nxt][rbase + (odd ^ 1)][w * 16 + col] = odd ? hx : hy;
      }
    }
    // single barrier per t: h staging + xs prefetch complete
    __syncthreads();
  }

  // tail: pred(6) from h(6) staged in Ah[SEQ&1] (= Ah[1])
  if (w < 2) {
    const int mt = w;
    floatx4 ap = (floatx4){0.f, 0.f, 0.f, 0.f};
#pragma unroll
    for (int kk = 0; kk < 4; ++kk) {
      half8 ah = *(const half8*)&Ah[1][mt * 16 + col][kk * 32 + quad * 8];
      half8 bo0 = *(const half8*)&Wo[(kk * 64 + lane) * 8];
      half8 bo1 = *(const half8*)&Wo[2048 + (kk * 64 + lane) * 8];
      ap = mfma16(ah, bo0, ap);
      ap = mfma16(ah, bo1, ap);
    }
    if (col == 0) {
#pragma unroll
      for (int r = 0; r < 4; ++r)
        out[(size_t)(rowbase + mt * 16 + quad * 4 + r) * 7 + 6] =
            ap[r] + bout;
    }
  }
}

extern "C" void kernel_launch(void* const* d_in, const int* in_sizes, int n_in,
                              void* d_out, int out_size, void* d_ws,
                              size_t ws_size, hipStream_t stream) {
  const float* x = (const float*)d_in[0];
  const float* x0 = (const float*)d_in[1];
  const float* Wih = (const float*)d_in[2];
  const float* Whh = (const float*)d_in[3];
  const float* bih = (const float*)d_in[4];
  const float* bhh = (const float*)d_in[5];
  const float* Wout = (const float*)d_in[6];
  const float* bout = (const float*)d_in[7];
  float* out = (float*)d_out;
  _Float16* Bp = (_Float16*)d_ws;  // 136 KB packed weights + wout frags

  pack_kernel<<<272, 256, 0, stream>>>(Whh, Wout, Bp);
  lstm_kernel<<<65536 / BT, 512, 0, stream>>>(x, x0, Wih, bih, bhh, bout, Bp,
                                              out);
}

// Round 15
// 145.241 us; speedup vs baseline: 1.1751x; 1.0216x over previous
//
#include <hip/hip_runtime.h>

// LSTM: HIDDEN=128, SEQ=7, BATCH=65536. fp32 in/out.
//
// R22 (= R21 with the cvt_pkrtz return-type fix: builtin returns
// __fp16x2, not _Float16x2; round 14 was a compile error, unrun).
// R21 theory: issue-count micro round on the R17/R20 plateau (94-95.5us).
// Port demand ~64us/CU; VALUBusy 50.6us measured; occupancy hard-capped
// at 4 waves/SIMD (bw=64 regs, tiers 64/128/256).
//  * acc-init in packed form (v_pk_fma_f32): 32 scalar fma -> 16 pk per t.
//  * v_cvt_pkrtz_f16_f32: one packed cvt per p instead of 2 scalar cvts
//    (RTZ ok: harness tolerance >= 4.88e-4, R19 evidence).
//  * R20's odd/even store swap reverted (measured neutral, costs selects).
// Unchanged: (512,4) 16 waves/CU 2 barrier domains, BT=32, weight-
// stationary bw AGPRs, MFMA-pred side column (Wo LDS), Tw/Tb LDS tables
// (volatile reads), packed exp2 fused-reciprocal epilogue, 1 barrier/t.

#define SEQ 7
#define BT 32

typedef _Float16 half8 __attribute__((ext_vector_type(8)));
typedef __fp16 fp16x2 __attribute__((ext_vector_type(2)));
typedef float floatx4 __attribute__((ext_vector_type(4)));
typedef float floatx2 __attribute__((ext_vector_type(2)));

__device__ __forceinline__ floatx4 mfma16(half8 a, half8 b, floatx4 c) {
  return __builtin_amdgcn_mfma_f32_16x16x32_f16(a, b, c, 0, 0, 0);
}

#define LOG2E 1.4426950408889634f
#define K2 2.885390081777927f  // 2*log2e

__device__ __forceinline__ floatx2 pexp2m(floatx2 v) {
  floatx2 r;
  r.x = __builtin_amdgcn_exp2f(-v.x);
  r.y = __builtin_amdgcn_exp2f(-v.y);
  return r;
}
__device__ __forceinline__ floatx2 prcp(floatx2 v) {
  floatx2 r;
  r.x = __builtin_amdgcn_rcpf(v.x);
  r.y = __builtin_amdgcn_rcpf(v.y);
  return r;
}

// Pack W_hh [512][128] fp32 -> B-fragment-major fp16, prescaled (idx<65536):
//   Bp[((nt*4+kk)*64 + lane)*8 + jj] = S(g) * Whh[j][k]
//   nt=g*8+w, j=g*128+w*16+col, k=32kk+8quad+jj.
// idx in [65536, 69632): W_out hi/lo fragments, col-0-only 16-col tile.
__global__ void pack_kernel(const float* __restrict__ Whh,
                            const float* __restrict__ Wout,
                            _Float16* __restrict__ Bp) {
  int idx = blockIdx.x * 256 + threadIdx.x;  // 0..69631
  if (idx < 65536) {
    int jj = idx & 7;
    int lane = (idx >> 3) & 63;
    int kk = (idx >> 9) & 3;
    int nt = idx >> 11;  // 0..31
    int g = nt >> 3, w = nt & 7;
    int col = lane & 15, quad = lane >> 4;
    int j = g * 128 + w * 16 + col;
    int k = 32 * kk + 8 * quad + jj;
    float S = (g == 2) ? K2 : LOG2E;
    Bp[idx] = (_Float16)(S * Whh[j * 128 + k]);
  } else {
    int pos = idx - 65536;  // 0..4095
    int hl = pos >> 11;     // 0 = hi, 1 = lo
    int e = pos & 2047;
    int jj = e & 7;
    int lane = (e >> 3) & 63;
    int kk = e >> 9;
    int col = lane & 15, quad = lane >> 4;
    int k = 32 * kk + 8 * quad + jj;
    float wv = Wout[k];
    _Float16 hi = (_Float16)wv;
    _Float16 v = hl ? (_Float16)(wv - (float)hi) : hi;
    Bp[idx] = (col == 0) ? v : (_Float16)0.0f;
  }
}

__launch_bounds__(512, 4)
__global__ void lstm_kernel(const float* __restrict__ x,
                            const float* __restrict__ x0,
                            const float* __restrict__ Wih,
                            const float* __restrict__ bih,
                            const float* __restrict__ bhh,
                            const float* __restrict__ boutp,
                            const _Float16* __restrict__ Bp,
                            float* __restrict__ out) {
  // h staged fp16, double-buffered, 272B row stride (+8 pad).
  __shared__ _Float16 Ah[2][BT][136];  // 17,408 B
  __shared__ float xs[2][BT];          // 256 B
  __shared__ _Float16 Wo[4096];        // 8 KB W_out hi/lo B-fragments
  __shared__ floatx4 Tw[8][16];        // 2 KB prescaled wih per (w,col)
  __shared__ floatx4 Tb[8][16];        // 2 KB prescaled bias per (w,col)

  const int tid = threadIdx.x;
  const int w = tid >> 6;  // wave 0..7: owns hcols [16w, 16w+16)
  const int lane = tid & 63;
  const int col = lane & 15;
  const int quad = lane >> 4;
  const int rowbase = blockIdx.x * BT;

  // stage W_out fragments into LDS (512 x 16B)
  ((half8*)Wo)[tid] = ((const half8*)(Bp + 65536))[tid];

  // build per-(w,col) prescaled wih/bias tables (16B entries)
  if (tid < 128) {
    int tw = tid >> 4, tc = tid & 15;
    float* pw = (float*)&Tw[tw][tc];
    float* pb = (float*)&Tb[tw][tc];
#pragma unroll
    for (int g = 0; g < 4; ++g) {
      int j = g * 128 + tw * 16 + tc;
      float S = (g == 2) ? K2 : LOG2E;
      pw[g] = S * Wih[j];
      pb[g] = S * (bih[j] + bhh[j]);
    }
  }

  // Gate-GEMM weight fragments: 64 regs (AGPR), loaded once.
  half8 bw[4][4];
#pragma unroll
  for (int g = 0; g < 4; ++g)
#pragma unroll
    for (int kk = 0; kk < 4; ++kk)
      bw[g][kk] =
          *(const half8*)(Bp + (((g * 8 + w) * 4 + kk) * 64 + lane) * 8);

  const float bout = boutp[0];

  // Scaled cell state c~ = 2log2e*c, pair-major float2 -> 8 registers.
  floatx2 c2[2][2];
#pragma unroll
  for (int mt = 0; mt < 2; ++mt)
#pragma unroll
    for (int p = 0; p < 2; ++p) c2[mt][p] = (floatx2){0.f, 0.f};

  if (tid < BT) xs[0][tid] = x0[rowbase + tid];  // t=0 consumes x0
  __syncthreads();

#pragma unroll 1
  for (int t = 0; t < SEQ; ++t) {
    const int cur = t & 1, nxt = cur ^ 1;

    // prefetch input for t+1 (consumes x[:, t])
    if (t + 1 < SEQ && tid < BT) {
      xs[nxt][tid] = x[(size_t)(rowbase + tid) * 7 + t];
    }

#pragma unroll
    for (int mt = 0; mt < 2; ++mt) {
      // x for the 4 rows (mt*16 + quad*4 + r) this lane covers.
      floatx4 xq = *(const floatx4*)&xs[cur][mt * 16 + quad * 4];

      // wih/bias from LDS, volatile so they stay transient (no re-hoist).
      floatx4 wihv = *(volatile const floatx4*)&Tw[w][col];
      floatx4 biasv = *(volatile const floatx4*)&Tb[w][col];

      // acc init = x*W_ih + bias, PACKED (v_pk_fma_f32 w/ op_sel extract).
      floatx4 acc[4];
#pragma unroll
      for (int g = 0; g < 4; ++g) acc[g] = xq * wihv[g] + biasv[g];

      const bool dopred = (w < 2) && (mt == w);  // wave-uniform

      if (t != 0) {  // h(0)=0: skip GEMM at t=0
        floatx4 ap = (floatx4){0.f, 0.f, 0.f, 0.f};  // pred(t-1) partial
#pragma unroll
        for (int kk = 0; kk < 4; ++kk) {
          half8 ah =
              *(const half8*)&Ah[cur][mt * 16 + col][kk * 32 + quad * 8];
#pragma unroll
          for (int g = 0; g < 4; ++g) acc[g] = mfma16(ah, bw[g][kk], acc[g]);
          if (dopred) {
            half8 bo0 = *(const half8*)&Wo[(kk * 64 + lane) * 8];
            half8 bo1 = *(const half8*)&Wo[2048 + (kk * 64 + lane) * 8];
            ap = mfma16(ah, bo0, ap);
            ap = mfma16(ah, bo1, ap);
          }
        }
        if (dopred && col == 0) {
#pragma unroll
          for (int r = 0; r < 4; ++r)
            out[(size_t)(rowbase + mt * 16 + quad * 4 + r) * 7 + (t - 1)] =
                ap[r] + bout;
        }
      }

      // Fused-reciprocal cell update, PACKED pairs (r01, r23).
      const floatx2 one2 = {1.0f, 1.0f};
      const floatx2 k22 = {K2, K2};
#pragma unroll
      for (int p = 0; p < 2; ++p) {
        floatx2 Gi, Gf, Gg, Go;
        Gi.x = acc[0][2 * p];
        Gi.y = acc[0][2 * p + 1];
        Gf.x = acc[1][2 * p];
        Gf.y = acc[1][2 * p + 1];
        Gg.x = acc[2][2 * p];
        Gg.y = acc[2][2 * p + 1];
        Go.x = acc[3][2 * p];
        Go.y = acc[3][2 * p + 1];
        floatx2 A = pexp2m(Gi);
        floatx2 Bv = pexp2m(Gf);
        floatx2 Cv = pexp2m(Gg);
        floatx2 Dv = pexp2m(Go);
        floatx2 a1 = A + one2;
        floatx2 b1 = Bv + one2;
        floatx2 c1 = Cv + one2;
        floatx2 ac = a1 * c1;
        floatx2 t1 = k22 - Cv * k22;
        floatx2 num = c2[mt][p] * ac + t1 * b1;
        floatx2 den = ac * b1;
        floatx2 cn = num * prcp(den);
        c2[mt][p] = cn;
        floatx2 E = pexp2m(cn);
        floatx2 de = (Dv + one2) * (E + one2);
        floatx2 hn = (one2 - E) * prcp(de);

        // stage h_new: one packed cvt (RTZ, __fp16x2 return), two b16
        // stores (lo + d16_hi halves of the same register).
        fp16x2 hp = __builtin_amdgcn_cvt_pkrtz(hn.x, hn.y);
        const int rbase = mt * 16 + quad * 4 + 2 * p;
        Ah[nxt][rbase][w * 16 + col] = (_Float16)hp.x;
        Ah[nxt][rbase + 1][w * 16 + col] = (_Float16)hp.y;
      }
    }
    // single barrier per t: h staging + xs prefetch complete
    __syncthreads();
  }

  // tail: pred(6) from h(6) staged in Ah[SEQ&1] (= Ah[1])
  if (w < 2) {
    const int mt = w;
    floatx4 ap = (floatx4){0.f, 0.f, 0.f, 0.f};
#pragma unroll
    for (int kk = 0; kk < 4; ++kk) {
      half8 ah = *(const half8*)&Ah[1][mt * 16 + col][kk * 32 + quad * 8];
      half8 bo0 = *(const half8*)&Wo[(kk * 64 + lane) * 8];
      half8 bo1 = *(const half8*)&Wo[2048 + (kk * 64 + lane) * 8];
      ap = mfma16(ah, bo0, ap);
      ap = mfma16(ah, bo1, ap);
    }
    if (col == 0) {
#pragma unroll
      for (int r = 0; r < 4; ++r)
        out[(size_t)(rowbase + mt * 16 + quad * 4 + r) * 7 + 6] =
            ap[r] + bout;
    }
  }
}

extern "C" void kernel_launch(void* const* d_in, const int* in_sizes, int n_in,
                              void* d_out, int out_size, void* d_ws,
                              size_t ws_size, hipStream_t stream) {
  const float* x = (const float*)d_in[0];
  const float* x0 = (const float*)d_in[1];
  const float* Wih = (const float*)d_in[2];
  const float* Whh = (const float*)d_in[3];
  const float* bih = (const float*)d_in[4];
  const float* bhh = (const float*)d_in[5];
  const float* Wout = (const float*)d_in[6];
  const float* bout = (const float*)d_in[7];
  float* out = (float*)d_out;
  _Float16* Bp = (_Float16*)d_ws;  // 136 KB packed weights + wout frags

  pack_kernel<<<272, 256, 0, stream>>>(Whh, Wout, Bp);
  lstm_kernel<<<65536 / BT, 512, 0, stream>>>(x, x0, Wih, bih, bhh, bout, Bp,
                                              out);
}